// Round 1
// baseline (408.823 us; speedup 1.0000x reference)
//
#include <hip/hip_runtime.h>

// ComposedCliffordSteerableKernel: 4096 independent tiny convs.
// out[co*4+n, ci*4+o, y, x] = sum_{c,ky,kx} k1[co*4+n, ci*4+c, y+ky-7, x+kx-7]
//                                         * k2[co*4+o, ci*4+c, ky, kx]
// (SAME padding, cross-correlation — jax.lax.conv does no kernel flip)

#define NCH   256   // co*4 = ci*4
#define KS    15
#define SP    225   // 15*15
#define AH    29    // padded image rows: y+ky in [0,28]
#define AW    32    // padded row width (16B-aligned chunks, XOR-swizzle friendly)
#define BW    16    // padded filter row width

__global__ __launch_bounds__(256, 2)
void blade_conv_kernel(const float* __restrict__ k1,
                       const float* __restrict__ k2,
                       float* __restrict__ out) {
    // As: [n][c][row][col ^ ((row&1)<<4)]  — zero-padded image block
    // Bs: [o][c][ky][kx] with kx=15 zeroed
    __shared__ __align__(16) float As[16 * AH * AW];   // 59392 B
    __shared__ __align__(16) float Bs[16 * KS * BW];   // 15360 B

    const int tid = threadIdx.x;
    const int co  = blockIdx.x;
    const int ci  = blockIdx.y;

    // ---- zero the padded image buffer ----
    for (int i = tid; i < 16 * AH * AW; i += 256) As[i] = 0.0f;
    __syncthreads();

    // ---- stage k1 interior (16 planes of 15x15) ----
    for (int idx = tid; idx < 16 * SP; idx += 256) {
        const int nc  = idx / SP;          // n*4 + c
        const int rem = idx % SP;
        const int y   = rem / KS;
        const int x   = rem % KS;
        const int n   = nc >> 2, c = nc & 3;
        const int row = y + 7;
        const int col = x + 7;
        const float v = k1[((size_t)((co * 4 + n) * NCH + (ci * 4 + c))) * SP + rem];
        As[(nc * AH + row) * AW + (col ^ ((row & 1) << 4))] = v;
    }
    // ---- stage k2 (16 planes, rows padded to 16, kx=15 -> 0) ----
    for (int idx = tid; idx < 16 * KS * BW; idx += 256) {
        const int oc  = idx / (KS * BW);   // o*4 + c
        const int rem = idx % (KS * BW);
        const int ky  = rem / BW;
        const int kx  = rem % BW;
        float v = 0.0f;
        if (kx < KS) {
            const int o = oc >> 2, c = oc & 3;
            v = k2[((size_t)((co * 4 + o) * NCH + (ci * 4 + c))) * SP + ky * KS + kx];
        }
        Bs[idx] = v;
    }
    __syncthreads();

    if (tid < 240) {
        const int n  = tid / 60;
        const int r  = tid % 60;
        const int y  = r >> 2;
        const int x0 = (r & 3) << 2;       // {0,4,8,12}; x = x0+dx, drop x==15

        float acc[4][4] = {};              // [o][dx]

        for (int c = 0; c < 4; ++c) {
            const float* aplane = &As[(n * 4 + c) * AH * AW];
            for (int ky = 0; ky < KS; ++ky) {
                const int row = y + ky;
                const int rp  = (row & 1) << 4;
                const float* ar = aplane + row * AW;

                float w[20];
                *(float4*)&w[0]  = *(const float4*)&ar[(x0     ) ^ rp];
                *(float4*)&w[4]  = *(const float4*)&ar[(x0 +  4) ^ rp];
                *(float4*)&w[8]  = *(const float4*)&ar[(x0 +  8) ^ rp];
                *(float4*)&w[12] = *(const float4*)&ar[(x0 + 12) ^ rp];
                *(float4*)&w[16] = *(const float4*)&ar[(x0 + 16) ^ rp];

                #pragma unroll
                for (int o = 0; o < 4; ++o) {
                    const float* br = &Bs[((o * 4 + c) * KS + ky) * BW];
                    float bv[16];
                    *(float4*)&bv[0]  = *(const float4*)&br[0];
                    *(float4*)&bv[4]  = *(const float4*)&br[4];
                    *(float4*)&bv[8]  = *(const float4*)&br[8];
                    *(float4*)&bv[12] = *(const float4*)&br[12];

                    #pragma unroll
                    for (int kx = 0; kx < KS; ++kx) {
                        #pragma unroll
                        for (int dx = 0; dx < 4; ++dx)
                            acc[o][dx] = fmaf(w[kx + dx], bv[kx], acc[o][dx]);
                    }
                }
            }
        }

        // ---- store ----
        const int orow = co * 4 + n;
        for (int o = 0; o < 4; ++o) {
            const int ocol = ci * 4 + o;
            float* op = out + (size_t)(orow * NCH + ocol) * SP + y * KS;
            #pragma unroll
            for (int dx = 0; dx < 4; ++dx) {
                const int x = x0 + dx;
                if (x < KS) op[x] = acc[o][dx];
            }
        }
    }
}

extern "C" void kernel_launch(void* const* d_in, const int* in_sizes, int n_in,
                              void* d_out, int out_size, void* d_ws, size_t ws_size,
                              hipStream_t stream) {
    (void)in_sizes; (void)n_in; (void)d_ws; (void)ws_size; (void)out_size;
    const float* k1 = (const float*)d_in[0];
    const float* k2 = (const float*)d_in[1];
    float* out = (float*)d_out;

    dim3 grid(64, 64, 1);
    dim3 block(256, 1, 1);
    hipLaunchKernelGGL(blade_conv_kernel, grid, block, 0, stream, k1, k2, out);
}

// Round 2
// 166.463 us; speedup vs baseline: 2.4559x; 2.4559x over previous
//
#include <hip/hip_runtime.h>

// out[co*4+n, ci*4+o, y, x] = sum_{c,ky,kx} k1[co*4+n, ci*4+c, y+ky-7, x+kx-7]
//                                         * k2[co*4+o, ci*4+c, ky, kx]
// MFMA formulation per (co,ci,c,ky):  OUT[y][(o,x)] += sum_u Apad[y+ky][u] * B[o][ky][u-x]
//   A-frag: lane(y = l&15, kgrp = l>>4) reads 8 contiguous bf16 -> ds_read_b128
//   B-frag: built in registers via ds_bpermute (lane-shift gather kx = u-x)
// 4 waves = 4 input channels c (independent, no barriers in K-loop), LDS slab reduce at end.

typedef float f32x4 __attribute__((ext_vector_type(4)));
typedef __bf16 bf16x8 __attribute__((ext_vector_type(8)));

#define KS 15
#define SP 225
#define NCH 256

__device__ __forceinline__ unsigned short f2bf(float f) {
    unsigned u = __builtin_bit_cast(unsigned, f);
    u += 0x7FFFu + ((u >> 16) & 1u);          // RNE (inputs are finite normals)
    return (unsigned short)(u >> 16);
}

__global__ __launch_bounds__(256, 2)
void blade_conv_mfma(const float* __restrict__ k1,
                     const float* __restrict__ k2,
                     float* __restrict__ out) {
    // phase 1: Apad bf16 [16 planes][30 rows][40 cols] = 38400 B @0
    //          Bsrc f32  [16 planes][225]              = 14400 B @38400
    // phase 2 (after sync): slabs f32 [4 waves][16 no][16 x][20 y] = 81920 B @0
    __shared__ __align__(16) unsigned char arena[81920];
    unsigned short* Apad = (unsigned short*)arena;
    float*          Bsrc = (float*)(arena + 38400);
    float*          slabs = (float*)arena;

    const int tid  = threadIdx.x;
    const int lane = tid & 63;
    const int wid  = tid >> 6;        // wave id == input channel c
    const int co = blockIdx.x, ci = blockIdx.y;

    // ---- zero padded A buffer ----
    f32x4 z = {0.f, 0.f, 0.f, 0.f};
    for (int i = tid; i < 2400; i += 256) ((f32x4*)arena)[i] = z;
    __syncthreads();

    // ---- stage k1 slice -> Apad (bf16, +7 pad), k2 slice -> Bsrc (f32) ----
    for (int idx = tid; idx < 16 * SP; idx += 256) {
        int nc = idx / SP, rem = idx % SP;
        int y = rem / KS, x = rem % KS;
        int n = nc >> 2, c = nc & 3;
        float v = k1[((size_t)((co * 4 + n) * NCH + ci * 4 + c)) * SP + rem];
        Apad[(nc * 30 + y + 7) * 40 + (x + 7)] = f2bf(v);
    }
    for (int idx = tid; idx < 16 * SP; idx += 256) {
        int oc = idx / SP, rem = idx % SP;
        int o = oc >> 2, c = oc & 3;
        Bsrc[idx] = k2[((size_t)((co * 4 + o) * NCH + ci * 4 + c)) * SP + rem];
    }
    __syncthreads();

    // ---- per-lane packed B source regs: lane kx holds (o0,o1) and (o2,o3) bf16 pairs ----
    const int kxl = lane & 15;
    int srcA[15], srcB[15];
    #pragma unroll
    for (int ky = 0; ky < 15; ++ky) {
        float b0 = 0.f, b1 = 0.f, b2 = 0.f, b3 = 0.f;
        if (kxl < 15) {
            int p = ky * KS + kxl;
            b0 = Bsrc[(0 * 4 + wid) * SP + p];
            b1 = Bsrc[(1 * 4 + wid) * SP + p];
            b2 = Bsrc[(2 * 4 + wid) * SP + p];
            b3 = Bsrc[(3 * 4 + wid) * SP + p];
        }
        srcA[ky] = (int)((unsigned)f2bf(b0) | ((unsigned)f2bf(b1) << 16));
        srcB[ky] = (int)((unsigned)f2bf(b2) | ((unsigned)f2bf(b3) << 16));
    }

    // ---- K loop: 15 chunks (ky), K=32 (u) each ----
    f32x4 acc[4][4];
    #pragma unroll
    for (int n = 0; n < 4; ++n)
        #pragma unroll
        for (int o = 0; o < 4; ++o)
            acc[n][o] = z;

    const int yl   = lane & 15;        // M index (output y)
    const int kg   = lane >> 4;        // k-group
    const int u0mx = (kg << 3) - kxl;  // u0 - x

    #pragma unroll
    for (int ky = 0; ky < 15; ++ky) {
        // A fragments: 4 planes (n), aligned 16B LDS reads
        bf16x8 af[4];
        #pragma unroll
        for (int n = 0; n < 4; ++n) {
            const unsigned short* p =
                &Apad[((n * 4 + wid) * 30 + yl + ky) * 40 + (kg << 3)];
            af[n] = *(const bf16x8*)p;
        }
        // B fragments via bpermute gather: kx_src = u0 + j - x
        unsigned r0[8], r1[8];
        #pragma unroll
        for (int j = 0; j < 8; ++j) {
            int ksrc = u0mx + j;
            int a4 = ksrc << 2;
            int t0 = __builtin_amdgcn_ds_bpermute(a4, srcA[ky]);
            int t1 = __builtin_amdgcn_ds_bpermute(a4, srcB[ky]);
            bool ok = (unsigned)ksrc <= 15u;   // kx in 0..15 (15 holds 0)
            r0[j] = ok ? (unsigned)t0 : 0u;
            r1[j] = ok ? (unsigned)t1 : 0u;
        }
        union { bf16x8 v; unsigned u[4]; } bo0, bo1, bo2, bo3;
        #pragma unroll
        for (int t = 0; t < 4; ++t) {
            unsigned lo = r0[2 * t], hi = r0[2 * t + 1];
            bo0.u[t] = (lo & 0xffffu) | (hi << 16);
            bo1.u[t] = (lo >> 16)     | (hi & 0xffff0000u);
            unsigned lo1 = r1[2 * t], hi1 = r1[2 * t + 1];
            bo2.u[t] = (lo1 & 0xffffu) | (hi1 << 16);
            bo3.u[t] = (lo1 >> 16)     | (hi1 & 0xffff0000u);
        }
        #pragma unroll
        for (int n = 0; n < 4; ++n) {
            acc[n][0] = __builtin_amdgcn_mfma_f32_16x16x32_bf16(af[n], bo0.v, acc[n][0], 0, 0, 0);
            acc[n][1] = __builtin_amdgcn_mfma_f32_16x16x32_bf16(af[n], bo1.v, acc[n][1], 0, 0, 0);
            acc[n][2] = __builtin_amdgcn_mfma_f32_16x16x32_bf16(af[n], bo2.v, acc[n][2], 0, 0, 0);
            acc[n][3] = __builtin_amdgcn_mfma_f32_16x16x32_bf16(af[n], bo3.v, acc[n][3], 0, 0, 0);
        }
    }

    // ---- cross-wave (c) reduction through LDS slabs ----
    __syncthreads();   // all waves done reading Apad/Bsrc; reuse arena
    {
        float* slab = slabs + wid * 5120;   // [16 no][16 x][20 y]
        #pragma unroll
        for (int n = 0; n < 4; ++n)
            #pragma unroll
            for (int o = 0; o < 4; ++o) {
                int no = n * 4 + o;
                *(f32x4*)&slab[(no * 16 + kxl) * 20 + (kg << 2)] = acc[n][o];
            }
    }
    __syncthreads();

    for (int idx = tid; idx < 16 * SP; idx += 256) {
        int no = idx / SP, rem = idx % SP;
        int yy = rem / KS, xx = rem % KS;
        int soff = (no * 16 + xx) * 20 + yy;
        float s = slabs[soff] + slabs[5120 + soff]
                + slabs[10240 + soff] + slabs[15360 + soff];
        int n = no >> 2, o = no & 3;
        out[((size_t)((co * 4 + n) * NCH + ci * 4 + o)) * SP + rem] = s;
    }
}

extern "C" void kernel_launch(void* const* d_in, const int* in_sizes, int n_in,
                              void* d_out, int out_size, void* d_ws, size_t ws_size,
                              hipStream_t stream) {
    (void)in_sizes; (void)n_in; (void)d_ws; (void)ws_size; (void)out_size;
    const float* k1 = (const float*)d_in[0];
    const float* k2 = (const float*)d_in[1];
    float* out = (float*)d_out;

    dim3 grid(64, 64, 1);
    dim3 block(256, 1, 1);
    hipLaunchKernelGGL(blade_conv_mfma, grid, block, 0, stream, k1, k2, out);
}

// Round 3
// 114.181 us; speedup vs baseline: 3.5805x; 1.4579x over previous
//
#include <hip/hip_runtime.h>

// out[co*4+n, ci*4+o, y, x] = sum_{c,ky,kx} k1[co*4+n, ci*4+c, y+ky-7, x+kx-7]
//                                         * k2[co*4+o, ci*4+c, ky, kx]
// MFMA per (co,ci,c,ky):  OUT[y][x] (o=0..3) += sum_u Apad[y+ky][u] * k2[o][ky][u-x]
//   A-frag: lane(y=l&15, kg=l>>4) reads 8 contiguous bf16 (ds_read_b128)
//   B-frag: register Toeplitz via ds_bpermute; source lanes 15..63 are ZERO so
//           out-of-range ksrc (wraps to 49..63, or 15..31) fetches 0 -> no cndmask.
// 4 waves = 4 input channels c; cross-wave c-reduction via two-round f32 LDS slab.

typedef float f32x4 __attribute__((ext_vector_type(4)));
typedef __bf16 bf16x8 __attribute__((ext_vector_type(8)));

#define KS 15
#define SP 225
#define NCH 256

__device__ __forceinline__ unsigned short f2bf(float f) {
    unsigned u = __builtin_bit_cast(unsigned, f);
    u += 0x7FFFu + ((u >> 16) & 1u);   // RNE (finite normals)
    return (unsigned short)(u >> 16);
}

__global__ __launch_bounds__(256, 3)
void blade_conv_mfma(const float* __restrict__ k1,
                     const float* __restrict__ k2,
                     float* __restrict__ out) {
    // phase 1: Apad bf16 [16 planes][30 rows][40 cols] = 38400 B
    // phase 2: slabs f32 [4 waves][8 no][16 x][20 y]   = 40960 B (overlaid)
    __shared__ __align__(16) unsigned char arena[40960];
    unsigned short* Apad  = (unsigned short*)arena;
    float*          slabs = (float*)arena;

    const int tid  = threadIdx.x;
    const int lane = tid & 63;
    const int wid  = tid >> 6;            // wave id == input channel c
    const int co = blockIdx.x, ci = blockIdx.y;

    // ---- zero padded A buffer ----
    f32x4 z = {0.f, 0.f, 0.f, 0.f};
    for (int i = tid; i < 2400; i += 256) ((f32x4*)arena)[i] = z;
    __syncthreads();

    // ---- stage k1 slice -> Apad (bf16, +7 pad) ----
    for (int idx = tid; idx < 16 * SP; idx += 256) {
        int nc = idx / SP, rem = idx % SP;
        int y = rem / KS, x = rem % KS;
        int n = nc >> 2, c = nc & 3;
        float v = k1[((size_t)((co * 4 + n) * NCH + ci * 4 + c)) * SP + rem];
        Apad[(nc * 30 + y + 7) * 40 + (x + 7)] = f2bf(v);
    }

    // ---- per-lane packed B sources straight from global (no LDS staging) ----
    // lane l<15 holds (o0,o1) and (o2,o3) bf16 pairs at kx=l; lanes 15..63 ZERO.
    int srcA[15], srcB[15];
    {
        const size_t base = ((size_t)(co * 4) * NCH + ci * 4 + wid) * SP;
        #pragma unroll
        for (int ky = 0; ky < 15; ++ky) {
            float b0 = 0.f, b1 = 0.f, b2 = 0.f, b3 = 0.f;
            if (lane < 15) {
                int p = ky * KS + lane;
                b0 = k2[base + 0 * NCH * SP + p];
                b1 = k2[base + 1 * NCH * SP + p];
                b2 = k2[base + 2 * NCH * SP + p];
                b3 = k2[base + 3 * NCH * SP + p];
            }
            srcA[ky] = (int)((unsigned)f2bf(b0) | ((unsigned)f2bf(b1) << 16));
            srcB[ky] = (int)((unsigned)f2bf(b2) | ((unsigned)f2bf(b3) << 16));
        }
    }
    __syncthreads();

    // ---- K loop: 15 ky chunks, K=32 (u) each ----
    f32x4 acc[4][4];
    #pragma unroll
    for (int n = 0; n < 4; ++n)
        #pragma unroll
        for (int o = 0; o < 4; ++o)
            acc[n][o] = z;

    const int yl   = lane & 15;        // output y
    const int kg   = lane >> 4;        // k-group
    const int u0mx = (kg << 3) - yl;   // NOTE: consuming lane's x == lane&15 == yl name reuse

    #pragma unroll
    for (int ky = 0; ky < 15; ++ky) {
        bf16x8 af[4];
        #pragma unroll
        for (int n = 0; n < 4; ++n) {
            const unsigned short* p =
                &Apad[((n * 4 + wid) * 30 + yl + ky) * 40 + (kg << 3)];
            af[n] = *(const bf16x8*)p;
        }
        unsigned r0[8], r1[8];
        #pragma unroll
        for (int j = 0; j < 8; ++j) {
            int a4 = (u0mx + j) << 2;
            r0[j] = (unsigned)__builtin_amdgcn_ds_bpermute(a4, srcA[ky]);
            r1[j] = (unsigned)__builtin_amdgcn_ds_bpermute(a4, srcB[ky]);
        }
        union { bf16x8 v; unsigned u[4]; } bo0, bo1, bo2, bo3;
        #pragma unroll
        for (int t = 0; t < 4; ++t) {
            unsigned lo = r0[2 * t], hi = r0[2 * t + 1];
            bo0.u[t] = (lo & 0xffffu) | (hi << 16);
            bo1.u[t] = (lo >> 16)     | (hi & 0xffff0000u);
            unsigned lo1 = r1[2 * t], hi1 = r1[2 * t + 1];
            bo2.u[t] = (lo1 & 0xffffu) | (hi1 << 16);
            bo3.u[t] = (lo1 >> 16)     | (hi1 & 0xffff0000u);
        }
        #pragma unroll
        for (int n = 0; n < 4; ++n) {
            acc[n][0] = __builtin_amdgcn_mfma_f32_16x16x32_bf16(af[n], bo0.v, acc[n][0], 0, 0, 0);
            acc[n][1] = __builtin_amdgcn_mfma_f32_16x16x32_bf16(af[n], bo1.v, acc[n][1], 0, 0, 0);
            acc[n][2] = __builtin_amdgcn_mfma_f32_16x16x32_bf16(af[n], bo2.v, acc[n][2], 0, 0, 0);
            acc[n][3] = __builtin_amdgcn_mfma_f32_16x16x32_bf16(af[n], bo3.v, acc[n][3], 0, 0, 0);
        }
    }

    // ---- cross-wave (c) reduction: two f32 rounds of 8 (n,o) tiles ----
    const int xl = lane & 15;
    #pragma unroll
    for (int g = 0; g < 2; ++g) {
        __syncthreads();   // g=0: waves done with Apad; g=1: readout of g=0 done
        {
            float* slab = slabs + wid * 2560;   // [8 no][16 x][20 y]
            #pragma unroll
            for (int nn = 0; nn < 2; ++nn)
                #pragma unroll
                for (int o = 0; o < 4; ++o) {
                    int no8 = nn * 4 + o;
                    *(f32x4*)&slab[(no8 * 16 + xl) * 20 + (kg << 2)] = acc[2 * g + nn][o];
                }
        }
        __syncthreads();
        for (int idx = tid; idx < 8 * SP; idx += 256) {
            int no8 = idx / SP, rem = idx % SP;
            int yy = rem / KS, xx = rem % KS;
            int soff = (no8 * 16 + xx) * 20 + yy;
            float s = slabs[soff] + slabs[2560 + soff]
                    + slabs[5120 + soff] + slabs[7680 + soff];
            int n = 2 * g + (no8 >> 2), o = no8 & 3;
            out[((size_t)((co * 4 + n) * NCH + ci * 4 + o)) * SP + rem] = s;
        }
    }
}

extern "C" void kernel_launch(void* const* d_in, const int* in_sizes, int n_in,
                              void* d_out, int out_size, void* d_ws, size_t ws_size,
                              hipStream_t stream) {
    (void)in_sizes; (void)n_in; (void)d_ws; (void)ws_size; (void)out_size;
    const float* k1 = (const float*)d_in[0];
    const float* k2 = (const float*)d_in[1];
    float* out = (float*)d_out;

    dim3 grid(64, 64, 1);
    dim3 block(256, 1, 1);
    hipLaunchKernelGGL(blade_conv_mfma, grid, block, 0, stream, k1, k2, out);
}

// Round 4
// 93.975 us; speedup vs baseline: 4.3503x; 1.2150x over previous
//
#include <hip/hip_runtime.h>

// out[co*4+n, ci*4+o, y, x] = sum_{c,ky,kx} k1[co*4+n, ci*4+c, y+ky-7, x+kx-7]
//                                         * k2[co*4+o, ci*4+c, ky, kx]
// MFMA per (co,ci,c,ky):  OUT[y][x] (o=0..3) += sum_u Apad[y+ky][u] * k2[o][ky][u-x]
//   A-frag: lane(y=l&15, kg=l>>4) reads 8 contiguous bf16 (ds_read_b128)
//   B-frag: register Toeplitz via ds_bpermute; src lanes 15..63 zero -> OOB fetches 0.
// 4 waves = 4 input channels c; c-reduction via 4 rounds of 4-tile f32 LDS slab.
// Arena 37120 B -> 4 blocks/CU (16 waves).

typedef float f32x4 __attribute__((ext_vector_type(4)));
typedef __bf16 bf16x8 __attribute__((ext_vector_type(8)));

#define KS 15
#define SP 225
#define NCH 256
#define AROWS 29
#define AW 40   // shorts per row: 80 B row stride (16B-aligned, good bank spread)

__device__ __forceinline__ unsigned short f2bf(float f) {
    unsigned u = __builtin_bit_cast(unsigned, f);
    u += 0x7FFFu + ((u >> 16) & 1u);   // RNE (finite normals)
    return (unsigned short)(u >> 16);
}

__global__ __launch_bounds__(256, 4)
void blade_conv_mfma(const float* __restrict__ k1,
                     const float* __restrict__ k2,
                     float* __restrict__ out) {
    // phase 1: Apad bf16 [16 planes][29 rows][40 cols] = 37120 B
    // phase 2: slabs f32 [4 wid][4 o][16 x][20 y]      = 20480 B (overlaid)
    __shared__ __align__(16) unsigned char arena[16 * AROWS * AW * 2];
    unsigned short* Apad  = (unsigned short*)arena;
    float*          slabs = (float*)arena;

    const int tid  = threadIdx.x;
    const int lane = tid & 63;
    const int wid  = tid >> 6;            // wave id == input channel c
    const int co = blockIdx.x, ci = blockIdx.y;

    // ---- k2 loads FIRST: latency overlaps zero+stage ----
    float b0[15], b1[15], b2[15], b3[15];
    {
        const size_t base = ((size_t)(co * 4) * NCH + ci * 4 + wid) * SP;
        #pragma unroll
        for (int ky = 0; ky < 15; ++ky) {
            b0[ky] = 0.f; b1[ky] = 0.f; b2[ky] = 0.f; b3[ky] = 0.f;
            if (lane < 15) {
                int p = ky * KS + lane;
                b0[ky] = k2[base + 0 * NCH * SP + p];
                b1[ky] = k2[base + 1 * NCH * SP + p];
                b2[ky] = k2[base + 2 * NCH * SP + p];
                b3[ky] = k2[base + 3 * NCH * SP + p];
            }
        }
    }

    // ---- zero padded A buffer ----
    f32x4 z = {0.f, 0.f, 0.f, 0.f};
    for (int i = tid; i < 16 * AROWS * AW / 8; i += 256) ((f32x4*)arena)[i] = z;
    __syncthreads();

    // ---- stage k1 slice -> Apad (bf16, +7 pad) ----
    for (int idx = tid; idx < 16 * SP; idx += 256) {
        int nc = idx / SP, rem = idx % SP;
        int y = rem / KS, x = rem % KS;
        int n = nc >> 2, c = nc & 3;
        float v = k1[((size_t)((co * 4 + n) * NCH + ci * 4 + c)) * SP + rem];
        Apad[(nc * AROWS + y + 7) * AW + (x + 7)] = f2bf(v);
    }

    // ---- pack k2 -> per-lane bpermute sources (lanes 15..63 zero) ----
    int srcA[15], srcB[15];
    #pragma unroll
    for (int ky = 0; ky < 15; ++ky) {
        srcA[ky] = (int)((unsigned)f2bf(b0[ky]) | ((unsigned)f2bf(b1[ky]) << 16));
        srcB[ky] = (int)((unsigned)f2bf(b2[ky]) | ((unsigned)f2bf(b3[ky]) << 16));
    }
    __syncthreads();

    // ---- K loop: 15 ky chunks, K=32 (u) each ----
    f32x4 acc[4][4];
    #pragma unroll
    for (int n = 0; n < 4; ++n)
        #pragma unroll
        for (int o = 0; o < 4; ++o)
            acc[n][o] = z;

    const int yl   = lane & 15;        // output y (M); also the consuming x for B
    const int kg   = lane >> 4;        // k-group
    const int u0mx = (kg << 3) - yl;   // u0 - x

    #pragma unroll
    for (int ky = 0; ky < 15; ++ky) {
        bf16x8 af[4];
        #pragma unroll
        for (int n = 0; n < 4; ++n) {
            const unsigned short* p =
                &Apad[((n * 4 + wid) * AROWS + yl + ky) * AW + (kg << 3)];
            af[n] = *(const bf16x8*)p;
        }
        unsigned r0[8], r1[8];
        #pragma unroll
        for (int j = 0; j < 8; ++j) {
            int a4 = (u0mx + j) << 2;
            r0[j] = (unsigned)__builtin_amdgcn_ds_bpermute(a4, srcA[ky]);
            r1[j] = (unsigned)__builtin_amdgcn_ds_bpermute(a4, srcB[ky]);
        }
        union { bf16x8 v; unsigned u[4]; } bo0, bo1, bo2, bo3;
        #pragma unroll
        for (int t = 0; t < 4; ++t) {
            // word t of o0-frag = (r0[2t].lo16, r0[2t+1].lo16); o1 = hi16s
            bo0.u[t] = __builtin_amdgcn_perm(r0[2 * t + 1], r0[2 * t], 0x05040100u);
            bo1.u[t] = __builtin_amdgcn_perm(r0[2 * t + 1], r0[2 * t], 0x07060302u);
            bo2.u[t] = __builtin_amdgcn_perm(r1[2 * t + 1], r1[2 * t], 0x05040100u);
            bo3.u[t] = __builtin_amdgcn_perm(r1[2 * t + 1], r1[2 * t], 0x07060302u);
        }
        #pragma unroll
        for (int n = 0; n < 4; ++n) {
            acc[n][0] = __builtin_amdgcn_mfma_f32_16x16x32_bf16(af[n], bo0.v, acc[n][0], 0, 0, 0);
            acc[n][1] = __builtin_amdgcn_mfma_f32_16x16x32_bf16(af[n], bo1.v, acc[n][1], 0, 0, 0);
            acc[n][2] = __builtin_amdgcn_mfma_f32_16x16x32_bf16(af[n], bo2.v, acc[n][2], 0, 0, 0);
            acc[n][3] = __builtin_amdgcn_mfma_f32_16x16x32_bf16(af[n], bo3.v, acc[n][3], 0, 0, 0);
        }
    }

    // ---- cross-wave (c) reduction: 4 rounds, 4 (o) tiles each (n = round) ----
    const int xl = lane & 15;
    #pragma unroll
    for (int g = 0; g < 4; ++g) {
        __syncthreads();   // g=0: Apad reads done; g>0: prev readout done
        {
            float* slab = slabs + wid * 1280;   // [4 o][16 x][20 y]
            #pragma unroll
            for (int o = 0; o < 4; ++o)
                *(f32x4*)&slab[(o * 16 + xl) * 20 + (kg << 2)] = acc[g][o];
        }
        __syncthreads();
        for (int idx = tid; idx < 4 * SP; idx += 256) {
            int o = idx / SP, rem = idx % SP;
            int yy = rem / KS, xx = rem % KS;
            int soff = (o * 16 + xx) * 20 + yy;
            float s = slabs[soff] + slabs[1280 + soff]
                    + slabs[2560 + soff] + slabs[3840 + soff];
            out[((size_t)((co * 4 + g) * NCH + ci * 4 + o)) * SP + rem] = s;
        }
    }
}

extern "C" void kernel_launch(void* const* d_in, const int* in_sizes, int n_in,
                              void* d_out, int out_size, void* d_ws, size_t ws_size,
                              hipStream_t stream) {
    (void)in_sizes; (void)n_in; (void)d_ws; (void)ws_size; (void)out_size;
    const float* k1 = (const float*)d_in[0];
    const float* k2 = (const float*)d_in[1];
    float* out = (float*)d_out;

    dim3 grid(64, 64, 1);
    dim3 block(256, 1, 1);
    hipLaunchKernelGGL(blade_conv_mfma, grid, block, 0, stream, k1, k2, out);
}